// Round 13
// baseline (824.568 us; speedup 1.0000x reference)
//
#include <hip/hip_runtime.h>
#include <hip/hip_bf16.h>
#include <cstdint>

#define DI __device__ __forceinline__

// B=4, T=2048, C=768, H=12, D=64
constexpr int Bz = 4, Tz = 2048, Cz = 768, Hz = 12, Dz = 64;
constexpr float QSCALE = 0.18033688011112042f;  // (1/8) * log2(e)

typedef __attribute__((ext_vector_type(4))) float f32x4;
typedef __attribute__((ext_vector_type(16))) float f32x16;
typedef __attribute__((ext_vector_type(8))) __bf16 bf16x8;
typedef __attribute__((ext_vector_type(4))) __bf16 bf16x4;
typedef __attribute__((ext_vector_type(2))) __bf16 bf16x2;

typedef __attribute__((address_space(1))) void gvoid;
typedef __attribute__((address_space(3))) void lvoid;

DI void gload16(const void* g, void* l) {
  __builtin_amdgcn_global_load_lds((gvoid*)g, (lvoid*)l, 16, 0, 0);
}

DI f32x4 mfma16(bf16x8 a, bf16x8 b, f32x4 c) {
  return __builtin_amdgcn_mfma_f32_16x16x32_bf16(a, b, c, 0, 0, 0);
}
DI f32x16 mfma32(bf16x8 a, bf16x8 b, f32x16 c) {
  return __builtin_amdgcn_mfma_f32_32x32x16_bf16(a, b, c, 0, 0, 0);
}

DI uint32_t pk2(float a, float b) {  // pack 2 f32 -> 2 bf16 in one u32
  bf16x2 t;
  t[0] = (__bf16)a;
  t[1] = (__bf16)b;
  return __builtin_bit_cast(uint32_t, t);
}

union FragU { bf16x8 v; uint32_t u[4]; };

// ---------------- one fused conversion kernel ----------------
__global__ void cvt_all_k(const float* __restrict__ x,
                          const float* __restrict__ wq, const float* __restrict__ wk,
                          const float* __restrict__ wv, __bf16* __restrict__ Xb,
                          __bf16* __restrict__ Wb) {
  int i = blockIdx.x * blockDim.x + threadIdx.x;  // < 2015232
  const float* s;
  __bf16* d;
  int r;
  if (i < 1572864) {
    s = x; d = Xb; r = i;
  } else {
    int j = i - 1572864;
    const int which = j / 147456;
    r = j - which * 147456;
    s = (which == 0) ? wq : (which == 1) ? wk : wv;
    d = Wb + which * 589824;  // 589824 bf16 elements per matrix
  }
  const float4 v = reinterpret_cast<const float4*>(s)[r];
  bf16x4 o = {(__bf16)v.x, (__bf16)v.y, (__bf16)v.z, (__bf16)v.w};
  reinterpret_cast<bf16x4*>(d)[r] = o;
}

// ---------------- fused QKV GEMM, 128x128 tile, BK=64 (r4-r10 form) ----
// Q pre-scaled by QSCALE; Q,K -> [bh][t][d]; V -> CHUNKED Vc[bh][k16][d][kc].
__global__ __launch_bounds__(256, 4) void qkv_gemm_k(
    const __bf16* __restrict__ Xb, const __bf16* __restrict__ Wb,
    const float* __restrict__ bq, const float* __restrict__ bk,
    const float* __restrict__ bv, __bf16* __restrict__ Qo,
    __bf16* __restrict__ Ko, __bf16* __restrict__ Vo) {
  __shared__ __align__(16) __bf16 As[128 * 64];
  __shared__ __align__(16) __bf16 Bs[128 * 64];

  const int tid = threadIdx.x;
  const int lane = tid & 63;
  const int w = tid >> 6;
  const int wr = w >> 1, wc = w & 1;
  const int g = lane >> 4, lr = lane & 15;

  const int wgid = (blockIdx.x & 7) * 144 + (blockIdx.x >> 3);
  const int tn = wgid % 18, tm = wgid / 18;
  const int m0 = tm * 128, n0 = tn * 128;

  f32x4 acc[4][4] = {};

  for (int kt = 0; kt < Cz; kt += 64) {
#pragma unroll
    for (int rep = 0; rep < 4; ++rep) {
      const int c = rep * 256 + tid;  // < 1024
      const int row = c >> 3, blk = c & 7;
      const int col = ((blk ^ (row & 7)) << 3);
      gload16(&Xb[(size_t)(m0 + row) * Cz + kt + col], &As[c << 3]);
      gload16(&Wb[(size_t)(n0 + row) * Cz + kt + col], &Bs[c << 3]);
    }
    __syncthreads();
#pragma unroll
    for (int kk = 0; kk < 2; ++kk) {
      bf16x8 a[4], b[4];
#pragma unroll
      for (int m = 0; m < 4; ++m) {
        const int row = wr * 64 + m * 16 + lr;
        a[m] = *reinterpret_cast<const bf16x8*>(
            &As[row * 64 + (((kk * 4 + g) ^ (row & 7)) << 3)]);
      }
#pragma unroll
      for (int n = 0; n < 4; ++n) {
        const int row = wc * 64 + n * 16 + lr;
        b[n] = *reinterpret_cast<const bf16x8*>(
            &Bs[row * 64 + (((kk * 4 + g) ^ (row & 7)) << 3)]);
      }
      __builtin_amdgcn_s_setprio(1);
#pragma unroll
      for (int m = 0; m < 4; ++m)
#pragma unroll
        for (int n = 0; n < 4; ++n) acc[m][n] = mfma16(a[m], b[n], acc[m][n]);
      __builtin_amdgcn_s_setprio(0);
    }
    __syncthreads();
  }

  // epilogue. tn 0-5 -> Q, 6-11 -> K, 12-17 -> V (uniform per block)
  const int bb = m0 >> 11;
  const int tbase = m0 & 2047;
  if (tn >= 12) {
#pragma unroll
    for (int n = 0; n < 4; ++n) {
      const int cc = (n0 - 1536) + wc * 64 + n * 16 + lr;
      const int h = cc >> 6, d = cc & 63;
      const float bsv = bv[cc];
      const int bh = bb * Hz + h;
#pragma unroll
      for (int m = 0; m < 4; ++m) {
        const int tloc = tbase + wr * 64 + m * 16 + g * 4;
        const int k16 = tloc >> 4;
        bf16x4 pkv;
#pragma unroll
        for (int j = 0; j < 4; ++j) pkv[j] = (__bf16)(acc[m][n][j] + bsv);
        *reinterpret_cast<bf16x4*>(
            &Vo[((size_t)(bh * 128 + k16) * 64 + d) * 16 + (tloc & 15)]) = pkv;
      }
    }
  } else {
    const bool isQ = (tn < 6);
#pragma unroll
    for (int n = 0; n < 4; ++n) {
      const int gn = n0 + wc * 64 + n * 16 + lr;
      const int cc = isQ ? gn : (gn - 768);
      const int h = cc >> 6, d = cc & 63;
      const float bsv = isQ ? bq[cc] : bk[cc];
      __bf16* dst = isQ ? Qo : Ko;
      const int bh = bb * Hz + h;
#pragma unroll
      for (int m = 0; m < 4; ++m) {
#pragma unroll
        for (int j = 0; j < 4; ++j) {
          const int t = tbase + wr * 64 + m * 16 + g * 4 + j;
          float v = acc[m][n][j] + bsv;
          if (isQ) v *= QSCALE;
          dst[(size_t)(bh * Tz + t) * Dz + d] = (__bf16)v;
        }
      }
    }
  }
}

// per-kblk compute: QK^T -> exp2 -> T12 pack -> PV. All-register.
// Uses in-scope: Ks, sub, off4, qB, vB, kt, hi, maskp, lpA, lpB, o0, o1.
#define KBLK_BODY(KBLK, MASKED)                                               \
  {                                                                           \
    bf16x8 kA0 = *reinterpret_cast<const bf16x8*>(                            \
        &Ks[sub][(KBLK)*2048 + off4[0]]);                                     \
    bf16x8 kA1 = *reinterpret_cast<const bf16x8*>(                            \
        &Ks[sub][(KBLK)*2048 + off4[1]]);                                     \
    bf16x8 kA2 = *reinterpret_cast<const bf16x8*>(                            \
        &Ks[sub][(KBLK)*2048 + off4[2]]);                                     \
    bf16x8 kA3 = *reinterpret_cast<const bf16x8*>(                            \
        &Ks[sub][(KBLK)*2048 + off4[3]]);                                     \
    f32x16 s = {};                                                            \
    __builtin_amdgcn_s_setprio(1);                                            \
    s = mfma32(kA0, qB[0], s);                                                \
    s = mfma32(kA1, qB[1], s);                                                \
    s = mfma32(kA2, qB[2], s);                                                \
    s = mfma32(kA3, qB[3], s);                                                \
    __builtin_amdgcn_s_setprio(0);                                            \
    float p[16];                                                              \
    _Pragma("unroll") for (int r = 0; r < 16; ++r) {                          \
      float sc = s[r];                                                        \
      if (MASKED) {                                                           \
        const int kg = kt + (KBLK)*32 + (r & 3) + 8 * (r >> 2) + 4 * hi;      \
        sc += (1.0f - maskp[kg]) * -14426.950408889634f;                      \
      }                                                                       \
      p[r] = __builtin_amdgcn_exp2f(sc);                                      \
      ((r & 1) ? lpB : lpA) += p[r];                                          \
    }                                                                         \
    uint32_t a0 = pk2(p[0], p[1]), a1 = pk2(p[4], p[5]);                      \
    uint32_t a2 = pk2(p[8], p[9]), a3 = pk2(p[12], p[13]);                    \
    uint32_t b0 = pk2(p[2], p[3]), b1 = pk2(p[6], p[7]);                      \
    uint32_t b2 = pk2(p[10], p[11]), b3 = pk2(p[14], p[15]);                  \
    asm volatile("v_permlane32_swap_b32 %0, %1" : "+v"(a0), "+v"(a1));        \
    asm volatile("v_permlane32_swap_b32 %0, %1" : "+v"(b0), "+v"(b1));        \
    asm volatile("v_permlane32_swap_b32 %0, %1" : "+v"(a2), "+v"(a3));        \
    asm volatile("v_permlane32_swap_b32 %0, %1" : "+v"(b2), "+v"(b3));        \
    FragU pf0, pf1;                                                           \
    pf0.u[0] = a0; pf0.u[1] = b0; pf0.u[2] = a1; pf0.u[3] = b1;               \
    pf1.u[0] = a2; pf1.u[1] = b2; pf1.u[2] = a3; pf1.u[3] = b3;               \
    __builtin_amdgcn_s_setprio(1);                                            \
    o0 = mfma32(pf0.v, vB[(KBLK)*2][0], o0);                                  \
    o1 = mfma32(pf0.v, vB[(KBLK)*2][1], o1);                                  \
    o0 = mfma32(pf1.v, vB[(KBLK)*2 + 1][0], o0);                              \
    o1 = mfma32(pf1.v, vB[(KBLK)*2 + 1][1], o1);                              \
    __builtin_amdgcn_s_setprio(0);                                            \
  }

// ---------------- flash attention, key-split across BLOCKS ----------------
// grid 1536 = 48 bh x 16 q-tiles x 2 key-halves, XCD-swizzled; 256 thr,
// 4 waves x 32 q. Each block = the r7/r10-proven body over ITS 1024 keys
// (16 tiles, 2-slot K double buffer, full __syncthreads per tile — no
// counted vmcnt, no new sync protocol). LDS 16.4KB + VGPR<=85 => 6
// blocks/CU = 24 waves/CU, entire grid co-resident (2x r10 occupancy).
// Combine: unnormalized O atomicAdd'ed into zeroed d_out (exactly 2
// commutative f32 adds per address -> bit-deterministic), l into lacc;
// separate norm kernel divides (kernel boundary = device-wide visibility,
// same mechanism that already passes Q/K/V between kernels).
__global__ __launch_bounds__(256, 6) void attn_acc_k(
    const __bf16* __restrict__ Qg, const __bf16* __restrict__ Kg,
    const __bf16* __restrict__ Vc, const float* __restrict__ mask,
    float* __restrict__ out, float* __restrict__ lacc) {
  __shared__ __align__(16) __bf16 Ks[2][4096];
  __shared__ int flag;

  const int tid = threadIdx.x;
  const int lane = tid & 63;
  const int w = tid >> 6;  // 0..3
  const int hi = lane >> 5;
  const int l31 = lane & 31;

  // bijective XCD swizzle (1536 % 8 == 0)
  const int wg = (blockIdx.x & 7) * 192 + (blockIdx.x >> 3);
  const int bh = wg >> 5;
  const int kh = (wg >> 4) & 1;
  const int qt = wg & 15;
  const int bb = bh / Hz, h = bh - bb * Hz;
  const int q0 = qt * 128 + w * 32;
  const int kbase = kh * 1024;  // this block's key range

  const size_t qkbase = (size_t)bh * Tz * Dz;
  const float* maskp = &mask[bb * Tz];

  if (tid == 0) flag = 0;
  __syncthreads();
  {
    int mybad = 0;
    for (int i = tid; i < Tz; i += 256) mybad |= (maskp[i] != 1.0f);
    if (__any(mybad) && lane == 0) atomicOr(&flag, 1);
  }

  // stage K tile 0 (keys kbase..kbase+63) into buf 0
#pragma unroll
  for (int rep = 0; rep < 2; ++rep) {
    const int c = rep * 256 + tid;  // < 512
    const int row = c >> 3, blk = c & 7;
    const int col = ((blk ^ (row & 7)) << 3);
    gload16(&Kg[qkbase + (size_t)(kbase + row) * Dz + col], &Ks[0][c << 3]);
  }

  // Q B-frags from global (pre-scaled): lane -> q = q0+l31, d = ks*16+hi*8
  bf16x8 qB[4];
#pragma unroll
  for (int ks = 0; ks < 4; ++ks)
    qB[ks] = *reinterpret_cast<const bf16x8*>(
        &Qg[qkbase + (size_t)(q0 + l31) * Dz + ks * 16 + hi * 8]);

  __syncthreads();  // flag final; K tile 0 staged and landed
  const bool use_mask = (flag != 0);

  // loop-invariant K LDS offsets; (row&7)==(l31&7), kblk adds 2048 elems
  int off4[4];
#pragma unroll
  for (int i = 0; i < 4; ++i)
    off4[i] = l31 * 64 + (((i * 2 + hi) ^ (l31 & 7)) << 3);

  // V chunk lane offset: d=dblk*32+l31 -> (within chunk) d*16 + hi*8
  const int vlane0 = l31 * 16 + hi * 8;
  const size_t vcb0 = qkbase + (size_t)kbase * Dz;  // chunked V, key-major

  f32x16 o0 = {}, o1 = {};
  float lpA = 0.f, lpB = 0.f;

  // 16 tiles, r7 top-barrier protocol: barrier drains stage(t) issued at
  // t-1 (RAW) and proves all waves done reading buf[sub^1] (WAR).
  for (int t2 = 0; t2 < 8; ++t2) {
#pragma unroll
    for (int sub = 0; sub < 2; ++sub) {
      const int t = 2 * t2 + sub;
      const int kt = kbase + t * 64;
      (void)kt;
      __syncthreads();
      // vB loads for this tile (coalesced 2KB/wave, L2-hot)
      bf16x8 vB[4][2];
#pragma unroll
      for (int ps4 = 0; ps4 < 4; ++ps4) {
        const size_t cbv = vcb0 + (size_t)t * 4096 + ps4 * 1024;
        vB[ps4][0] = *reinterpret_cast<const bf16x8*>(&Vc[cbv + vlane0]);
        vB[ps4][1] = *reinterpret_cast<const bf16x8*>(&Vc[cbv + 512 + vlane0]);
      }
      // prefetch K tile t+1 into buf sub^1
      if (t < 15) {
#pragma unroll
        for (int rep = 0; rep < 2; ++rep) {
          const int c = rep * 256 + tid;
          const int row = c >> 3, blk = c & 7;
          const int col = ((blk ^ (row & 7)) << 3);
          gload16(&Kg[qkbase + (size_t)(kt + 64 + row) * Dz + col],
                  &Ks[sub ^ 1][c << 3]);
        }
      }
      if (use_mask) {
        KBLK_BODY(0, true)
        KBLK_BODY(1, true)
      } else {
        KBLK_BODY(0, false)
        KBLK_BODY(1, false)
      }
    }
  }

  // epilogue: accumulate into global (exact: no-max softmax is
  // order-independent; 2 commutative f32 adds per address).
  float lp = lpA + lpB;
  float lfin = lp + __shfl_xor(lp, 32);  // both key-subsets of this half
  if (lane < 32) atomicAdd(&lacc[bh * Tz + q0 + l31], lfin);
#pragma unroll
  for (int r = 0; r < 16; ++r) {
    const int qr = (r & 3) + 8 * (r >> 2) + 4 * hi;
    float* orow = &out[(size_t)(bb * Tz + q0 + qr) * Cz + h * Dz + l31];
    atomicAdd(&orow[0], o0[r]);
    atomicAdd(&orow[32], o1[r]);
  }
}

// ---------------- normalize: out /= l ----------------
__global__ void norm_k(float* __restrict__ out, const float* __restrict__ lacc) {
  const int idx = blockIdx.x * 256 + threadIdx.x;  // < 1572864 float4s
  float4 v = reinterpret_cast<float4*>(out)[idx];
  const int i4 = idx * 4;
  const int b = i4 / (Tz * Cz);
  const int rem = i4 - b * (Tz * Cz);
  const int t = rem / Cz;
  const int c = rem - t * Cz;  // float4 never crosses a d-64 boundary
  const float inv = 1.0f / lacc[(b * Hz + (c >> 6)) * Tz + t];
  v.x *= inv; v.y *= inv; v.z *= inv; v.w *= inv;
  reinterpret_cast<float4*>(out)[idx] = v;
}

// ---------------- launcher ----------------
extern "C" void kernel_launch(void* const* d_in, const int* in_sizes, int n_in,
                              void* d_out, int out_size, void* d_ws,
                              size_t ws_size, hipStream_t stream) {
  const float* x = (const float*)d_in[0];
  const float* mask = (const float*)d_in[1];
  const float* Wq = (const float*)d_in[2];
  const float* bq = (const float*)d_in[3];
  const float* Wk = (const float*)d_in[4];
  const float* bk = (const float*)d_in[5];
  const float* Wv = (const float*)d_in[6];
  const float* bv = (const float*)d_in[7];
  float* out = (float*)d_out;

  char* ws = (char*)d_ws;
  __bf16* Xb = (__bf16*)ws;                              // 8192*768 bf16 (dead after GEMM)
  __bf16* Wb = (__bf16*)(ws + 12582912);                 // 2304*768 bf16 (dead after GEMM)
  __bf16* Qb = (__bf16*)(ws + 16131072);                 // [bh][t][d], pre-scaled
  __bf16* Kb = (__bf16*)(ws + 16131072 + 12582912);      // [bh][t][d]
  __bf16* Vb = (__bf16*)(ws + 16131072 + 2 * 12582912);  // chunked [bh][k16][d][kc]
  float* lacc = (float*)ws;  // 48*2048 f32 = 393KB, overlays DEAD Xb (zeroed after GEMM)

  cvt_all_k<<<7872, 256, 0, stream>>>(x, Wq, Wk, Wv, Xb, Wb);
  qkv_gemm_k<<<1152, 256, 0, stream>>>(Xb, Wb, bq, bk, bv, Qb, Kb, Vb);
  hipMemsetAsync(out, 0, (size_t)Bz * Tz * Cz * sizeof(float), stream);
  hipMemsetAsync(lacc, 0, (size_t)48 * Tz * sizeof(float), stream);
  attn_acc_k<<<1536, 256, 0, stream>>>(Qb, Kb, Vb, mask, out, lacc);
  norm_k<<<6144, 256, 0, stream>>>(out, lacc);
}

// Round 14
// 268.261 us; speedup vs baseline: 3.0738x; 3.0738x over previous
//
#include <hip/hip_runtime.h>
#include <hip/hip_bf16.h>
#include <cstdint>

#define DI __device__ __forceinline__

// B=4, T=2048, C=768, H=12, D=64
constexpr int Bz = 4, Tz = 2048, Cz = 768, Hz = 12, Dz = 64;
constexpr float QSCALE = 0.18033688011112042f;  // (1/8) * log2(e)

typedef __attribute__((ext_vector_type(4))) float f32x4;
typedef __attribute__((ext_vector_type(16))) float f32x16;
typedef __attribute__((ext_vector_type(8))) __bf16 bf16x8;
typedef __attribute__((ext_vector_type(4))) __bf16 bf16x4;
typedef __attribute__((ext_vector_type(2))) __bf16 bf16x2;

typedef __attribute__((address_space(1))) void gvoid;
typedef __attribute__((address_space(3))) void lvoid;

DI void gload16(const void* g, void* l) {
  __builtin_amdgcn_global_load_lds((gvoid*)g, (lvoid*)l, 16, 0, 0);
}

DI f32x4 mfma16(bf16x8 a, bf16x8 b, f32x4 c) {
  return __builtin_amdgcn_mfma_f32_16x16x32_bf16(a, b, c, 0, 0, 0);
}
DI f32x16 mfma32(bf16x8 a, bf16x8 b, f32x16 c) {
  return __builtin_amdgcn_mfma_f32_32x32x16_bf16(a, b, c, 0, 0, 0);
}

DI uint32_t pk2(float a, float b) {  // pack 2 f32 -> 2 bf16 in one u32
  bf16x2 t;
  t[0] = (__bf16)a;
  t[1] = (__bf16)b;
  return __builtin_bit_cast(uint32_t, t);
}

union FragU { bf16x8 v; uint32_t u[4]; };

// ---------------- one fused conversion kernel ----------------
__global__ void cvt_all_k(const float* __restrict__ x,
                          const float* __restrict__ wq, const float* __restrict__ wk,
                          const float* __restrict__ wv, __bf16* __restrict__ Xb,
                          __bf16* __restrict__ Wb) {
  int i = blockIdx.x * blockDim.x + threadIdx.x;  // < 2015232
  const float* s;
  __bf16* d;
  int r;
  if (i < 1572864) {
    s = x; d = Xb; r = i;
  } else {
    int j = i - 1572864;
    const int which = j / 147456;
    r = j - which * 147456;
    s = (which == 0) ? wq : (which == 1) ? wk : wv;
    d = Wb + which * 589824;  // 589824 bf16 elements per matrix
  }
  const float4 v = reinterpret_cast<const float4*>(s)[r];
  bf16x4 o = {(__bf16)v.x, (__bf16)v.y, (__bf16)v.z, (__bf16)v.w};
  reinterpret_cast<bf16x4*>(d)[r] = o;
}

// ---------------- fused QKV GEMM, 128x128 tile, BK=64 (r4-r10 form) ----
// Q pre-scaled by QSCALE; Q,K -> [bh][t][d]; V -> CHUNKED Vc[bh][k16][d][kc].
__global__ __launch_bounds__(256, 4) void qkv_gemm_k(
    const __bf16* __restrict__ Xb, const __bf16* __restrict__ Wb,
    const float* __restrict__ bq, const float* __restrict__ bk,
    const float* __restrict__ bv, __bf16* __restrict__ Qo,
    __bf16* __restrict__ Ko, __bf16* __restrict__ Vo) {
  __shared__ __align__(16) __bf16 As[128 * 64];
  __shared__ __align__(16) __bf16 Bs[128 * 64];

  const int tid = threadIdx.x;
  const int lane = tid & 63;
  const int w = tid >> 6;
  const int wr = w >> 1, wc = w & 1;
  const int g = lane >> 4, lr = lane & 15;

  const int wgid = (blockIdx.x & 7) * 144 + (blockIdx.x >> 3);
  const int tn = wgid % 18, tm = wgid / 18;
  const int m0 = tm * 128, n0 = tn * 128;

  f32x4 acc[4][4] = {};

  for (int kt = 0; kt < Cz; kt += 64) {
#pragma unroll
    for (int rep = 0; rep < 4; ++rep) {
      const int c = rep * 256 + tid;  // < 1024
      const int row = c >> 3, blk = c & 7;
      const int col = ((blk ^ (row & 7)) << 3);
      gload16(&Xb[(size_t)(m0 + row) * Cz + kt + col], &As[c << 3]);
      gload16(&Wb[(size_t)(n0 + row) * Cz + kt + col], &Bs[c << 3]);
    }
    __syncthreads();
#pragma unroll
    for (int kk = 0; kk < 2; ++kk) {
      bf16x8 a[4], b[4];
#pragma unroll
      for (int m = 0; m < 4; ++m) {
        const int row = wr * 64 + m * 16 + lr;
        a[m] = *reinterpret_cast<const bf16x8*>(
            &As[row * 64 + (((kk * 4 + g) ^ (row & 7)) << 3)]);
      }
#pragma unroll
      for (int n = 0; n < 4; ++n) {
        const int row = wc * 64 + n * 16 + lr;
        b[n] = *reinterpret_cast<const bf16x8*>(
            &Bs[row * 64 + (((kk * 4 + g) ^ (row & 7)) << 3)]);
      }
      __builtin_amdgcn_s_setprio(1);
#pragma unroll
      for (int m = 0; m < 4; ++m)
#pragma unroll
        for (int n = 0; n < 4; ++n) acc[m][n] = mfma16(a[m], b[n], acc[m][n]);
      __builtin_amdgcn_s_setprio(0);
    }
    __syncthreads();
  }

  // epilogue. tn 0-5 -> Q, 6-11 -> K, 12-17 -> V (uniform per block)
  const int bb = m0 >> 11;
  const int tbase = m0 & 2047;
  if (tn >= 12) {
#pragma unroll
    for (int n = 0; n < 4; ++n) {
      const int cc = (n0 - 1536) + wc * 64 + n * 16 + lr;
      const int h = cc >> 6, d = cc & 63;
      const float bsv = bv[cc];
      const int bh = bb * Hz + h;
#pragma unroll
      for (int m = 0; m < 4; ++m) {
        const int tloc = tbase + wr * 64 + m * 16 + g * 4;
        const int k16 = tloc >> 4;
        bf16x4 pkv;
#pragma unroll
        for (int j = 0; j < 4; ++j) pkv[j] = (__bf16)(acc[m][n][j] + bsv);
        *reinterpret_cast<bf16x4*>(
            &Vo[((size_t)(bh * 128 + k16) * 64 + d) * 16 + (tloc & 15)]) = pkv;
      }
    }
  } else {
    const bool isQ = (tn < 6);
#pragma unroll
    for (int n = 0; n < 4; ++n) {
      const int gn = n0 + wc * 64 + n * 16 + lr;
      const int cc = isQ ? gn : (gn - 768);
      const int h = cc >> 6, d = cc & 63;
      const float bsv = isQ ? bq[cc] : bk[cc];
      __bf16* dst = isQ ? Qo : Ko;
      const int bh = bb * Hz + h;
#pragma unroll
      for (int m = 0; m < 4; ++m) {
#pragma unroll
        for (int j = 0; j < 4; ++j) {
          const int t = tbase + wr * 64 + m * 16 + g * 4 + j;
          float v = acc[m][n][j] + bsv;
          if (isQ) v *= QSCALE;
          dst[(size_t)(bh * Tz + t) * Dz + d] = (__bf16)v;
        }
      }
    }
  }
}

// per-kblk compute: QK^T -> exp2 -> T12 pack -> PV. All-register.
// Uses in-scope: Ks, sub, off4, qB, vB, kt, hi, maskp, lpA, lpB, o0, o1.
#define KBLK_BODY(KBLK, MASKED)                                               \
  {                                                                           \
    bf16x8 kA0 = *reinterpret_cast<const bf16x8*>(                            \
        &Ks[sub][(KBLK)*2048 + off4[0]]);                                     \
    bf16x8 kA1 = *reinterpret_cast<const bf16x8*>(                            \
        &Ks[sub][(KBLK)*2048 + off4[1]]);                                     \
    bf16x8 kA2 = *reinterpret_cast<const bf16x8*>(                            \
        &Ks[sub][(KBLK)*2048 + off4[2]]);                                     \
    bf16x8 kA3 = *reinterpret_cast<const bf16x8*>(                            \
        &Ks[sub][(KBLK)*2048 + off4[3]]);                                     \
    f32x16 s = {};                                                            \
    __builtin_amdgcn_s_setprio(1);                                            \
    s = mfma32(kA0, qB[0], s);                                                \
    s = mfma32(kA1, qB[1], s);                                                \
    s = mfma32(kA2, qB[2], s);                                                \
    s = mfma32(kA3, qB[3], s);                                                \
    __builtin_amdgcn_s_setprio(0);                                            \
    float p[16];                                                              \
    _Pragma("unroll") for (int r = 0; r < 16; ++r) {                          \
      float sc = s[r];                                                        \
      if (MASKED) {                                                           \
        const int kg = kt + (KBLK)*32 + (r & 3) + 8 * (r >> 2) + 4 * hi;      \
        sc += (1.0f - maskp[kg]) * -14426.950408889634f;                      \
      }                                                                       \
      p[r] = __builtin_amdgcn_exp2f(sc);                                      \
      ((r & 1) ? lpB : lpA) += p[r];                                          \
    }                                                                         \
    uint32_t a0 = pk2(p[0], p[1]), a1 = pk2(p[4], p[5]);                      \
    uint32_t a2 = pk2(p[8], p[9]), a3 = pk2(p[12], p[13]);                    \
    uint32_t b0 = pk2(p[2], p[3]), b1 = pk2(p[6], p[7]);                      \
    uint32_t b2 = pk2(p[10], p[11]), b3 = pk2(p[14], p[15]);                  \
    asm volatile("v_permlane32_swap_b32 %0, %1" : "+v"(a0), "+v"(a1));        \
    asm volatile("v_permlane32_swap_b32 %0, %1" : "+v"(b0), "+v"(b1));        \
    asm volatile("v_permlane32_swap_b32 %0, %1" : "+v"(a2), "+v"(a3));        \
    asm volatile("v_permlane32_swap_b32 %0, %1" : "+v"(b2), "+v"(b3));        \
    FragU pf0, pf1;                                                           \
    pf0.u[0] = a0; pf0.u[1] = b0; pf0.u[2] = a1; pf0.u[3] = b1;               \
    pf1.u[0] = a2; pf1.u[1] = b2; pf1.u[2] = a3; pf1.u[3] = b3;               \
    __builtin_amdgcn_s_setprio(1);                                            \
    o0 = mfma32(pf0.v, vB[(KBLK)*2][0], o0);                                  \
    o1 = mfma32(pf0.v, vB[(KBLK)*2][1], o1);                                  \
    o0 = mfma32(pf1.v, vB[(KBLK)*2 + 1][0], o0);                              \
    o1 = mfma32(pf1.v, vB[(KBLK)*2 + 1][1], o1);                              \
    __builtin_amdgcn_s_setprio(0);                                            \
  }

// ---------------- flash attention, key-split across BLOCKS ----------------
// grid 1536 = 48 bh x 16 q-tiles x 2 key-halves, XCD-swizzled; 256 thr,
// 4 waves x 32 q. Each block = the r7/r10-proven body over ITS 1024 keys.
// r14 fix vs r13: __launch_bounds__(256,4) (VGPR cap 128) instead of
// (256,6) (cap 85) -- r13's forced cap spilled everything (VGPR=40,
// FETCH 1.2GB). The body compiles to ~84 VGPR unconstrained (r10), and
// 84 VGPR * 6 waves = 504 <= 512/SIMD, LDS 16.9KB * 6 <= 160KB: the
// RUNTIME occupancy reaches 6 blocks/CU (24 waves/CU) without any forced
// cap. Combine: atomicAdd unnormalized O into zeroed out (exactly 2
// commutative f32 adds per address -> deterministic), l into lacc;
// norm kernel divides.
__global__ __launch_bounds__(256, 4) void attn_acc_k(
    const __bf16* __restrict__ Qg, const __bf16* __restrict__ Kg,
    const __bf16* __restrict__ Vc, const float* __restrict__ mask,
    float* __restrict__ out, float* __restrict__ lacc) {
  __shared__ __align__(16) __bf16 Ks[2][4096];
  __shared__ int flag;

  const int tid = threadIdx.x;
  const int lane = tid & 63;
  const int w = tid >> 6;  // 0..3
  const int hi = lane >> 5;
  const int l31 = lane & 31;

  // bijective XCD swizzle (1536 % 8 == 0)
  const int wg = (blockIdx.x & 7) * 192 + (blockIdx.x >> 3);
  const int bh = wg >> 5;
  const int kh = (wg >> 4) & 1;
  const int qt = wg & 15;
  const int bb = bh / Hz, h = bh - bb * Hz;
  const int q0 = qt * 128 + w * 32;
  const int kbase = kh * 1024;  // this block's key range

  const size_t qkbase = (size_t)bh * Tz * Dz;
  const float* maskp = &mask[bb * Tz];

  if (tid == 0) flag = 0;
  __syncthreads();
  {
    int mybad = 0;
    for (int i = tid; i < Tz; i += 256) mybad |= (maskp[i] != 1.0f);
    if (__any(mybad) && lane == 0) atomicOr(&flag, 1);
  }

  // stage K tile 0 (keys kbase..kbase+63) into buf 0
#pragma unroll
  for (int rep = 0; rep < 2; ++rep) {
    const int c = rep * 256 + tid;  // < 512
    const int row = c >> 3, blk = c & 7;
    const int col = ((blk ^ (row & 7)) << 3);
    gload16(&Kg[qkbase + (size_t)(kbase + row) * Dz + col], &Ks[0][c << 3]);
  }

  // Q B-frags from global (pre-scaled): lane -> q = q0+l31, d = ks*16+hi*8
  bf16x8 qB[4];
#pragma unroll
  for (int ks = 0; ks < 4; ++ks)
    qB[ks] = *reinterpret_cast<const bf16x8*>(
        &Qg[qkbase + (size_t)(q0 + l31) * Dz + ks * 16 + hi * 8]);

  __syncthreads();  // flag final; K tile 0 staged and landed
  const bool use_mask = (flag != 0);

  // loop-invariant K LDS offsets; (row&7)==(l31&7), kblk adds 2048 elems
  int off4[4];
#pragma unroll
  for (int i = 0; i < 4; ++i)
    off4[i] = l31 * 64 + (((i * 2 + hi) ^ (l31 & 7)) << 3);

  // V chunk lane offset: d=dblk*32+l31 -> (within chunk) d*16 + hi*8
  const int vlane0 = l31 * 16 + hi * 8;
  const size_t vcb0 = qkbase + (size_t)kbase * Dz;  // chunked V, key-major

  f32x16 o0 = {}, o1 = {};
  float lpA = 0.f, lpB = 0.f;

  // 16 tiles, r7 top-barrier protocol: barrier drains stage(t) issued at
  // t-1 (RAW) and proves all waves done reading buf[sub^1] (WAR).
  for (int t2 = 0; t2 < 8; ++t2) {
#pragma unroll
    for (int sub = 0; sub < 2; ++sub) {
      const int t = 2 * t2 + sub;
      const int kt = kbase + t * 64;
      (void)kt;
      __syncthreads();
      // vB loads for this tile (coalesced 2KB/wave, L2-hot)
      bf16x8 vB[4][2];
#pragma unroll
      for (int ps4 = 0; ps4 < 4; ++ps4) {
        const size_t cbv = vcb0 + (size_t)t * 4096 + ps4 * 1024;
        vB[ps4][0] = *reinterpret_cast<const bf16x8*>(&Vc[cbv + vlane0]);
        vB[ps4][1] = *reinterpret_cast<const bf16x8*>(&Vc[cbv + 512 + vlane0]);
      }
      // prefetch K tile t+1 into buf sub^1
      if (t < 15) {
#pragma unroll
        for (int rep = 0; rep < 2; ++rep) {
          const int c = rep * 256 + tid;
          const int row = c >> 3, blk = c & 7;
          const int col = ((blk ^ (row & 7)) << 3);
          gload16(&Kg[qkbase + (size_t)(kt + 64 + row) * Dz + col],
                  &Ks[sub ^ 1][c << 3]);
        }
      }
      if (use_mask) {
        KBLK_BODY(0, true)
        KBLK_BODY(1, true)
      } else {
        KBLK_BODY(0, false)
        KBLK_BODY(1, false)
      }
    }
  }

  // epilogue: accumulate into global (exact: no-max softmax is
  // order-independent; 2 commutative f32 adds per address).
  float lp = lpA + lpB;
  float lfin = lp + __shfl_xor(lp, 32);  // both key-subsets of this half
  if (lane < 32) atomicAdd(&lacc[bh * Tz + q0 + l31], lfin);
#pragma unroll
  for (int r = 0; r < 16; ++r) {
    const int qr = (r & 3) + 8 * (r >> 2) + 4 * hi;
    float* orow = &out[(size_t)(bb * Tz + q0 + qr) * Cz + h * Dz + l31];
    atomicAdd(&orow[0], o0[r]);
    atomicAdd(&orow[32], o1[r]);
  }
}

// ---------------- normalize: out /= l ----------------
__global__ void norm_k(float* __restrict__ out, const float* __restrict__ lacc) {
  const int idx = blockIdx.x * 256 + threadIdx.x;  // < 1572864 float4s
  float4 v = reinterpret_cast<float4*>(out)[idx];
  const int i4 = idx * 4;
  const int b = i4 / (Tz * Cz);
  const int rem = i4 - b * (Tz * Cz);
  const int t = rem / Cz;
  const int c = rem - t * Cz;  // float4 never crosses a d-64 boundary
  const float inv = 1.0f / lacc[(b * Hz + (c >> 6)) * Tz + t];
  v.x *= inv; v.y *= inv; v.z *= inv; v.w *= inv;
  reinterpret_cast<float4*>(out)[idx] = v;
}

// ---------------- launcher ----------------
extern "C" void kernel_launch(void* const* d_in, const int* in_sizes, int n_in,
                              void* d_out, int out_size, void* d_ws,
                              size_t ws_size, hipStream_t stream) {
  const float* x = (const float*)d_in[0];
  const float* mask = (const float*)d_in[1];
  const float* Wq = (const float*)d_in[2];
  const float* bq = (const float*)d_in[3];
  const float* Wk = (const float*)d_in[4];
  const float* bk = (const float*)d_in[5];
  const float* Wv = (const float*)d_in[6];
  const float* bv = (const float*)d_in[7];
  float* out = (float*)d_out;

  char* ws = (char*)d_ws;
  __bf16* Xb = (__bf16*)ws;                              // 8192*768 bf16 (dead after GEMM)
  __bf16* Wb = (__bf16*)(ws + 12582912);                 // 2304*768 bf16 (dead after GEMM)
  __bf16* Qb = (__bf16*)(ws + 16131072);                 // [bh][t][d], pre-scaled
  __bf16* Kb = (__bf16*)(ws + 16131072 + 12582912);      // [bh][t][d]
  __bf16* Vb = (__bf16*)(ws + 16131072 + 2 * 12582912);  // chunked [bh][k16][d][kc]
  float* lacc = (float*)ws;  // 48*2048 f32 = 393KB, overlays DEAD Xb

  cvt_all_k<<<7872, 256, 0, stream>>>(x, Wq, Wk, Wv, Xb, Wb);
  qkv_gemm_k<<<1152, 256, 0, stream>>>(Xb, Wb, bq, bk, bv, Qb, Kb, Vb);
  hipMemsetAsync(out, 0, (size_t)Bz * Tz * Cz * sizeof(float), stream);
  hipMemsetAsync(lacc, 0, (size_t)48 * Tz * sizeof(float), stream);
  attn_acc_k<<<1536, 256, 0, stream>>>(Qb, Kb, Vb, mask, out, lacc);
  norm_k<<<6144, 256, 0, stream>>>(out, lacc);
}